// Round 1
// baseline (952.113 us; speedup 1.0000x reference)
//
#include <hip/hip_runtime.h>
#include <hip/hip_bf16.h>
#include <math.h>

#define NEG_SLOPE 0.2f

// ---------------- GEMM: h1lin = x@W1, proj = x@Wp (fused over 256 cols) ----
// BM=64, BN=64, BK=16, 256 threads, 4x4 microtile.
__global__ __launch_bounds__(256) void gemm_fused(
    const float* __restrict__ x, const float* __restrict__ W1,
    const float* __restrict__ Wp, float* __restrict__ h1lin,
    float* __restrict__ proj) {
  __shared__ float As[16][68];   // [k][m], stride 68 -> 2-way max on writes
  __shared__ float Bs[16][64];   // [k][n]
  const int tid = threadIdx.x;
  const int row0 = blockIdx.x * 64;
  const int col0 = blockIdx.y * 64;  // 0..255 over [W1|Wp]
  const float* B = (col0 < 128) ? W1 : Wp;
  const int bcol = (col0 < 128) ? col0 : col0 - 128;

  const int tx = tid & 15, ty = tid >> 4;
  const int alk = tid & 15, am = tid >> 4;  // A: k=alk, rows am+16i
  const int bn = tid & 63, bk = tid >> 6;   // B: n=bn, k=bk+4i

  float acc[4][4] = {};
  for (int k0 = 0; k0 < 768; k0 += 16) {
#pragma unroll
    for (int i = 0; i < 4; i++)
      As[alk][am + i * 16] = x[(size_t)(row0 + am + i * 16) * 768 + k0 + alk];
#pragma unroll
    for (int i = 0; i < 4; i++)
      Bs[bk + i * 4][bn] = B[(size_t)(k0 + bk + i * 4) * 128 + bcol + bn];
    __syncthreads();
#pragma unroll
    for (int kk = 0; kk < 16; kk++) {
      float4 a4 = *(const float4*)&As[kk][ty * 4];
      float4 b4 = *(const float4*)&Bs[kk][tx * 4];
      float av[4] = {a4.x, a4.y, a4.z, a4.w};
      float bv[4] = {b4.x, b4.y, b4.z, b4.w};
#pragma unroll
      for (int i = 0; i < 4; i++)
#pragma unroll
        for (int j = 0; j < 4; j++) acc[i][j] += av[i] * bv[j];
    }
    __syncthreads();
  }
  float* Cout = (col0 < 128) ? h1lin : proj;
  const int ccol = bcol;
#pragma unroll
  for (int i = 0; i < 4; i++) {
    int r = row0 + ty * 4 + i;
    float4 v = make_float4(acc[i][0], acc[i][1], acc[i][2], acc[i][3]);
    *(float4*)&Cout[(size_t)r * 128 + ccol + tx * 4] = v;
  }
}

// ---------------- per-node attention logits for layer 1 --------------------
// a_s1[n][h] = sum_c h1lin[n][h*16+c]*att_src1[h][c]; same for a_d1.
__global__ __launch_bounds__(128) void attn1(
    const float* __restrict__ h1lin, const float* __restrict__ att_src1,
    const float* __restrict__ att_dst1, float* __restrict__ a_s1,
    float* __restrict__ a_d1) {
  const int n = blockIdx.x, t = threadIdx.x;
  float v = h1lin[(size_t)n * 128 + t];
  float as = v * att_src1[t];
  float ad = v * att_dst1[t];
#pragma unroll
  for (int off = 8; off; off >>= 1) {
    as += __shfl_xor(as, off);
    ad += __shfl_xor(ad, off);
  }
  if ((t & 15) == 0) {
    a_s1[n * 8 + (t >> 4)] = as;
    a_d1[n * 8 + (t >> 4)] = ad;
  }
}

// ---------------- counting sort of edges by dst ----------------------------
__global__ void init_counts(int* counts, int N) {
  int i = blockIdx.x * blockDim.x + threadIdx.x;
  if (i < N) counts[i] = 1;  // self loop
}

__global__ void hist_kernel(const int* __restrict__ dst, int* counts, int E) {
  int i = blockIdx.x * blockDim.x + threadIdx.x;
  int stride = gridDim.x * blockDim.x;
  for (; i < E; i += stride) atomicAdd(&counts[dst[i]], 1);
}

__global__ __launch_bounds__(256) void scan_a(const int* __restrict__ counts,
                                              int* offsets, int* bsum) {
  __shared__ int s[256];
  int t = threadIdx.x, idx = blockIdx.x * 256 + t;
  int v = counts[idx];
  s[t] = v;
  __syncthreads();
  for (int d = 1; d < 256; d <<= 1) {
    int x = (t >= d) ? s[t - d] : 0;
    __syncthreads();
    s[t] += x;
    __syncthreads();
  }
  offsets[idx] = s[t] - v;
  if (t == 255) bsum[blockIdx.x] = s[t];
}

__global__ __launch_bounds__(256) void scan_b(int* bsum) {
  __shared__ int s[256];
  int t = threadIdx.x;
  int v = bsum[t];
  s[t] = v;
  __syncthreads();
  for (int d = 1; d < 256; d <<= 1) {
    int x = (t >= d) ? s[t - d] : 0;
    __syncthreads();
    s[t] += x;
    __syncthreads();
  }
  bsum[t] = s[t] - v;
}

__global__ __launch_bounds__(256) void scan_c(int* offsets, const int* bsum,
                                              int* cursor, int N, int Etot) {
  int t = threadIdx.x, idx = blockIdx.x * 256 + t;
  int off = offsets[idx] + bsum[blockIdx.x];
  offsets[idx] = off;
  cursor[idx] = off;
  if (idx == 0) offsets[N] = Etot;
}

__global__ void scatter_edges(const int* __restrict__ src,
                              const int* __restrict__ dst, int* cursor,
                              int* sortedsrc, int E) {
  int i = blockIdx.x * blockDim.x + threadIdx.x;
  int stride = gridDim.x * blockDim.x;
  for (; i < E; i += stride) {
    int pos = atomicAdd(&cursor[dst[i]], 1);
    sortedsrc[pos] = src[i];
  }
}

__global__ void scatter_self(int* cursor, int* sortedsrc, int N) {
  int i = blockIdx.x * blockDim.x + threadIdx.x;
  if (i < N) {
    int pos = atomicAdd(&cursor[i], 1);
    sortedsrc[pos] = i;
  }
}

// ---------------- layer-1 aggregation + residual + ELU ---------------------
// one block (128 thr) per node; thread t handles channel t (head = t/16).
__global__ __launch_bounds__(128) void agg1(
    const float* __restrict__ h1lin, const float* __restrict__ proj,
    const float* __restrict__ a_s1, const float* __restrict__ a_d1,
    const int* __restrict__ offsets, const int* __restrict__ sortedsrc,
    const float* __restrict__ b1, const float* __restrict__ bp,
    float* __restrict__ hmid) {
  const int n = blockIdx.x, t = threadIdx.x;
  const int h = t >> 4;
  const float ad = a_d1[n * 8 + h];
  const int begin = offsets[n], end = offsets[n + 1];
  float acc = 0.f, aw = 0.f;
  for (int j = begin; j < end; j++) {
    int s = sortedsrc[j];
    float e = a_s1[s * 8 + h] + ad;
    float lr = e > 0.f ? e : NEG_SLOPE * e;
    float w = __expf(lr);
    acc += w * h1lin[(size_t)s * 128 + t];
    aw += w;
  }
  float v = acc / (aw + 1e-16f) + b1[t] + proj[(size_t)n * 128 + t] + bp[t];
  hmid[(size_t)n * 128 + t] = v > 0.f ? v : (__expf(v) - 1.f);
}

// ---------------- layer-2 features + attention logits ----------------------
__global__ __launch_bounds__(128) void feat2(
    const float* __restrict__ hmid, const float* __restrict__ W2,
    const float* __restrict__ att_s2, const float* __restrict__ att_d2,
    float* __restrict__ h2, float* __restrict__ as2, float* __restrict__ ad2) {
  const int n = blockIdx.x, t = threadIdx.x;
  float v = hmid[(size_t)n * 128 + t];
  float p0 = v * W2[2 * t], p1 = v * W2[2 * t + 1];
#pragma unroll
  for (int off = 32; off; off >>= 1) {
    p0 += __shfl_xor(p0, off);
    p1 += __shfl_xor(p1, off);
  }
  __shared__ float sred[4];
  if ((t & 63) == 0) {
    sred[(t >> 6) * 2] = p0;
    sred[(t >> 6) * 2 + 1] = p1;
  }
  __syncthreads();
  if (t == 0) {
    float h20 = sred[0] + sred[2], h21 = sred[1] + sred[3];
    h2[2 * n] = h20;
    h2[2 * n + 1] = h21;
    as2[n] = h20 * att_s2[0] + h21 * att_s2[1];
    ad2[n] = h20 * att_d2[0] + h21 * att_d2[1];
  }
}

// ---------------- layer-2 aggregation (wave per node) ----------------------
__global__ __launch_bounds__(256) void agg2(
    const float* __restrict__ h2, const float* __restrict__ as2,
    const float* __restrict__ ad2, const int* __restrict__ offsets,
    const int* __restrict__ sortedsrc, const float* __restrict__ b2,
    float* __restrict__ out, int N) {
  const int node = blockIdx.x * 4 + (threadIdx.x >> 6);
  const int lane = threadIdx.x & 63;
  if (node >= N) return;
  const int begin = offsets[node], end = offsets[node + 1];
  const float ad = ad2[node];
  float acc0 = 0.f, acc1 = 0.f, aw = 0.f;
  for (int j = begin + lane; j < end; j += 64) {
    int s = sortedsrc[j];
    float e = as2[s] + ad;
    float lr = e > 0.f ? e : NEG_SLOPE * e;
    float w = __expf(lr);
    acc0 += w * h2[2 * s];
    acc1 += w * h2[2 * s + 1];
    aw += w;
  }
#pragma unroll
  for (int off = 32; off; off >>= 1) {
    acc0 += __shfl_xor(acc0, off);
    acc1 += __shfl_xor(acc1, off);
    aw += __shfl_xor(aw, off);
  }
  if (lane == 0) {
    float inv = 1.f / (aw + 1e-16f);
    out[2 * node] = acc0 * inv + b2[0];
    out[2 * node + 1] = acc1 * inv + b2[1];
  }
}

extern "C" void kernel_launch(void* const* d_in, const int* in_sizes, int n_in,
                              void* d_out, int out_size, void* d_ws,
                              size_t ws_size, hipStream_t stream) {
  const float* x = (const float*)d_in[0];
  const int* edge_index = (const int*)d_in[1];
  const float* W1 = (const float*)d_in[2];
  const float* att_src1 = (const float*)d_in[3];
  const float* att_dst1 = (const float*)d_in[4];
  const float* b1 = (const float*)d_in[5];
  const float* Wp = (const float*)d_in[6];
  const float* bp = (const float*)d_in[7];
  const float* W2 = (const float*)d_in[8];
  const float* att_src2 = (const float*)d_in[9];
  const float* att_dst2 = (const float*)d_in[10];
  const float* b2 = (const float*)d_in[11];
  float* out = (float*)d_out;

  const int N = in_sizes[0] / 768;
  const int E = in_sizes[1] / 2;
  const int Etot = E + N;
  const int* src = edge_index;
  const int* dst = edge_index + E;

  // workspace carve-up
  char* ws = (char*)d_ws;
  size_t off = 0;
  auto alloc = [&](size_t bytes) {
    size_t cur = off;
    off += (bytes + 255) & ~(size_t)255;
    return (void*)(ws + cur);
  };
  float* h1lin = (float*)alloc((size_t)N * 128 * 4);
  float* proj = (float*)alloc((size_t)N * 128 * 4);
  float* hmid = (float*)alloc((size_t)N * 128 * 4);
  float* a_s1 = (float*)alloc((size_t)N * 8 * 4);
  float* a_d1 = (float*)alloc((size_t)N * 8 * 4);
  float* h2 = (float*)alloc((size_t)N * 2 * 4);
  float* as2 = (float*)alloc((size_t)N * 4);
  float* ad2 = (float*)alloc((size_t)N * 4);
  int* counts = (int*)alloc((size_t)N * 4);
  int* offsets = (int*)alloc(((size_t)N + 1) * 4);
  int* cursor = (int*)alloc((size_t)N * 4);
  int* bsum = (int*)alloc(256 * 4);
  int* sortedsrc = (int*)alloc((size_t)Etot * 4);

  // 1. fused GEMM: h1lin = x@W1, proj = x@Wp
  gemm_fused<<<dim3(N / 64, 4), 256, 0, stream>>>(x, W1, Wp, h1lin, proj);
  // 2. layer-1 attention logits
  attn1<<<N, 128, 0, stream>>>(h1lin, att_src1, att_dst1, a_s1, a_d1);
  // 3. counting sort by dst (self loops included)
  init_counts<<<(N + 255) / 256, 256, 0, stream>>>(counts, N);
  hist_kernel<<<5120, 256, 0, stream>>>(dst, counts, E);
  scan_a<<<N / 256, 256, 0, stream>>>(counts, offsets, bsum);
  scan_b<<<1, 256, 0, stream>>>(bsum);
  scan_c<<<N / 256, 256, 0, stream>>>(offsets, bsum, cursor, N, Etot);
  scatter_edges<<<5120, 256, 0, stream>>>(src, dst, cursor, sortedsrc, E);
  scatter_self<<<(N + 255) / 256, 256, 0, stream>>>(cursor, sortedsrc, N);
  // 4. layer-1 aggregation + residual + ELU
  agg1<<<N, 128, 0, stream>>>(h1lin, proj, a_s1, a_d1, offsets, sortedsrc, b1,
                              bp, hmid);
  // 5. layer-2 features + logits
  feat2<<<N, 128, 0, stream>>>(hmid, W2, att_src2, att_dst2, h2, as2, ad2);
  // 6. layer-2 aggregation -> output
  agg2<<<(N + 3) / 4, 256, 0, stream>>>(h2, as2, ad2, offsets, sortedsrc, b2,
                                        out, N);
}

// Round 2
// 652.921 us; speedup vs baseline: 1.4582x; 1.4582x over previous
//
#include <hip/hip_runtime.h>
#include <hip/hip_bf16.h>
#include <math.h>

#define NEG_SLOPE 0.2f

typedef __attribute__((ext_vector_type(8))) short short8;
typedef __attribute__((ext_vector_type(4))) float float4v;

__device__ __forceinline__ unsigned f2bf(float f) {
  unsigned u = __builtin_bit_cast(unsigned, f);
  return (u + 0x7fffu + ((u >> 16) & 1u)) >> 16;  // RNE
}

// ---------------- weight pre-transpose: Wt[c][k] bf16, c in [0,256) --------
__global__ __launch_bounds__(256) void convert_w(const float* __restrict__ W1,
                                                 const float* __restrict__ Wp,
                                                 short* __restrict__ Wt) {
  int k = blockIdx.x;   // 0..767
  int c = threadIdx.x;  // 0..255
  float v = (c < 128) ? W1[k * 128 + c] : Wp[k * 128 + (c - 128)];
  Wt[(size_t)c * 768 + k] = (short)f2bf(v);
}

// ---------------- bf16 MFMA GEMM: [h1lin|proj] = x @ [W1|Wp] ---------------
// BM=128, BN=256 (all cols -> x read once), BK=32, 256 thr (4 waves),
// wave w covers cols [w*64, w*64+64). 16x16x32 MFMA.
__global__ __launch_bounds__(256) void gemm_mfma(const float* __restrict__ x,
                                                 const short* __restrict__ Wt,
                                                 float* __restrict__ h1lin,
                                                 float* __restrict__ proj) {
  __shared__ short As[128][40];  // [row][k], pad 32->40 (2-way max on frag reads)
  __shared__ short Bs[256][40];  // [col][k] == B^T
  const int tid = threadIdx.x;
  const int wave = tid >> 6, lane = tid & 63;
  const int l15 = lane & 15, l4 = lane >> 4;
  const int row0 = blockIdx.x * 128;

  const int ar = tid >> 3;        // row within 32-row group
  const int ak = (tid & 7) * 4;   // k offset (4 floats)
  const int bc = tid >> 2;        // col within 64-col group
  const int bk = (tid & 3) * 8;   // k offset (8 bf16)

  float4v acc[8][4] = {};

  for (int k0 = 0; k0 < 768; k0 += 32) {
    // stage A: 128x32 fp32 -> bf16 LDS
#pragma unroll
    for (int i = 0; i < 4; i++) {
      int r = i * 32 + ar;
      float4 f = *(const float4*)&x[(size_t)(row0 + r) * 768 + k0 + ak];
      uint2 p;
      p.x = f2bf(f.x) | (f2bf(f.y) << 16);
      p.y = f2bf(f.z) | (f2bf(f.w) << 16);
      *(uint2*)&As[r][ak] = p;  // 8B aligned: (r*40+ak)*2
    }
    // stage B: 256x32 bf16 LDS (already bf16 in Wt)
#pragma unroll
    for (int i = 0; i < 4; i++) {
      int c = i * 64 + bc;
      uint4 v = *(const uint4*)&Wt[(size_t)c * 768 + k0 + bk];
      *(uint4*)&Bs[c][bk] = v;  // 16B aligned
    }
    __syncthreads();

    short8 afr[8];
#pragma unroll
    for (int rt = 0; rt < 8; rt++)
      afr[rt] = *(const short8*)&As[rt * 16 + l15][l4 * 8];
#pragma unroll
    for (int ct = 0; ct < 4; ct++) {
      short8 bfr = *(const short8*)&Bs[wave * 64 + ct * 16 + l15][l4 * 8];
#pragma unroll
      for (int rt = 0; rt < 8; rt++)
        acc[rt][ct] =
            __builtin_amdgcn_mfma_f32_16x16x32_bf16(afr[rt], bfr, acc[rt][ct], 0, 0, 0);
    }
    __syncthreads();
  }

  // epilogue: C/D layout col=lane&15, row=(lane>>4)*4+reg
  const int colbase = wave * 64;
#pragma unroll
  for (int ct = 0; ct < 4; ct++) {
    int c = colbase + ct * 16 + l15;
    float* Cout = (c < 128) ? h1lin : proj;
    int cc = c & 127;
#pragma unroll
    for (int rt = 0; rt < 8; rt++) {
#pragma unroll
      for (int r = 0; r < 4; r++) {
        int R = row0 + rt * 16 + l4 * 4 + r;
        Cout[(size_t)R * 128 + cc] = acc[rt][ct][r];
      }
    }
  }
}

// ---------------- per-node attention logits for layer 1 --------------------
__global__ __launch_bounds__(128) void attn1(
    const float* __restrict__ h1lin, const float* __restrict__ att_src1,
    const float* __restrict__ att_dst1, float* __restrict__ a_s1,
    float* __restrict__ a_d1) {
  const int n = blockIdx.x, t = threadIdx.x;
  float v = h1lin[(size_t)n * 128 + t];
  float as = v * att_src1[t];
  float ad = v * att_dst1[t];
#pragma unroll
  for (int off = 8; off; off >>= 1) {
    as += __shfl_xor(as, off);
    ad += __shfl_xor(ad, off);
  }
  if ((t & 15) == 0) {
    a_s1[n * 8 + (t >> 4)] = as;
    a_d1[n * 8 + (t >> 4)] = ad;
  }
}

// ---------------- counting sort of edges by dst ----------------------------
__global__ void init_counts(int* counts, int N) {
  int i = blockIdx.x * blockDim.x + threadIdx.x;
  if (i < N) counts[i] = 1;  // self loop
}

__global__ void hist_kernel(const int* __restrict__ dst, int* counts, int E) {
  int i = blockIdx.x * blockDim.x + threadIdx.x;
  int stride = gridDim.x * blockDim.x;
  for (; i < E; i += stride) atomicAdd(&counts[dst[i]], 1);
}

__global__ __launch_bounds__(256) void scan_a(const int* __restrict__ counts,
                                              int* offsets, int* bsum) {
  __shared__ int s[256];
  int t = threadIdx.x, idx = blockIdx.x * 256 + t;
  int v = counts[idx];
  s[t] = v;
  __syncthreads();
  for (int d = 1; d < 256; d <<= 1) {
    int x = (t >= d) ? s[t - d] : 0;
    __syncthreads();
    s[t] += x;
    __syncthreads();
  }
  offsets[idx] = s[t] - v;
  if (t == 255) bsum[blockIdx.x] = s[t];
}

__global__ __launch_bounds__(256) void scan_b(int* bsum) {
  __shared__ int s[256];
  int t = threadIdx.x;
  int v = bsum[t];
  s[t] = v;
  __syncthreads();
  for (int d = 1; d < 256; d <<= 1) {
    int x = (t >= d) ? s[t - d] : 0;
    __syncthreads();
    s[t] += x;
    __syncthreads();
  }
  bsum[t] = s[t] - v;
}

__global__ __launch_bounds__(256) void scan_c(int* offsets, const int* bsum,
                                              int* cursor, int N, int Etot) {
  int t = threadIdx.x, idx = blockIdx.x * 256 + t;
  int off = offsets[idx] + bsum[blockIdx.x];
  offsets[idx] = off;
  cursor[idx] = off;
  if (idx == 0) offsets[N] = Etot;
}

__global__ void scatter_edges(const int* __restrict__ src,
                              const int* __restrict__ dst, int* cursor,
                              int* sortedsrc, int E) {
  int i = blockIdx.x * blockDim.x + threadIdx.x;
  int stride = gridDim.x * blockDim.x;
  for (; i < E; i += stride) {
    int pos = atomicAdd(&cursor[dst[i]], 1);
    sortedsrc[pos] = src[i];
  }
}

__global__ void scatter_self(int* cursor, int* sortedsrc, int N) {
  int i = blockIdx.x * blockDim.x + threadIdx.x;
  if (i < N) {
    int pos = atomicAdd(&cursor[i], 1);
    sortedsrc[pos] = i;
  }
}

// ---------------- layer-1 aggregation + residual + ELU ---------------------
// one block (128 thr) per node; thread t = channel t (head = t/16).
// 4-deep software pipeline on the edge gathers.
__global__ __launch_bounds__(128) void agg1(
    const float* __restrict__ h1lin, const float* __restrict__ proj,
    const float* __restrict__ a_s1, const float* __restrict__ a_d1,
    const int* __restrict__ offsets, const int* __restrict__ sortedsrc,
    const float* __restrict__ b1, const float* __restrict__ bp,
    float* __restrict__ hmid) {
  const int n = blockIdx.x, t = threadIdx.x;
  const int h = t >> 4;
  const float ad = a_d1[n * 8 + h];
  const int begin = offsets[n], end = offsets[n + 1];
  float acc = 0.f, aw = 0.f;
  int j = begin;
  for (; j + 4 <= end; j += 4) {
    int s0 = sortedsrc[j], s1 = sortedsrc[j + 1];
    int s2 = sortedsrc[j + 2], s3 = sortedsrc[j + 3];
    float e0 = a_s1[s0 * 8 + h], e1 = a_s1[s1 * 8 + h];
    float e2 = a_s1[s2 * 8 + h], e3 = a_s1[s3 * 8 + h];
    float v0 = h1lin[(size_t)s0 * 128 + t], v1 = h1lin[(size_t)s1 * 128 + t];
    float v2 = h1lin[(size_t)s2 * 128 + t], v3 = h1lin[(size_t)s3 * 128 + t];
    e0 += ad; e1 += ad; e2 += ad; e3 += ad;
    float w0 = __expf(e0 > 0.f ? e0 : NEG_SLOPE * e0);
    float w1 = __expf(e1 > 0.f ? e1 : NEG_SLOPE * e1);
    float w2 = __expf(e2 > 0.f ? e2 : NEG_SLOPE * e2);
    float w3 = __expf(e3 > 0.f ? e3 : NEG_SLOPE * e3);
    acc += w0 * v0 + w1 * v1 + w2 * v2 + w3 * v3;
    aw += (w0 + w1) + (w2 + w3);
  }
  for (; j < end; j++) {
    int s = sortedsrc[j];
    float e = a_s1[s * 8 + h] + ad;
    float w = __expf(e > 0.f ? e : NEG_SLOPE * e);
    acc += w * h1lin[(size_t)s * 128 + t];
    aw += w;
  }
  float v = acc / (aw + 1e-16f) + b1[t] + proj[(size_t)n * 128 + t] + bp[t];
  hmid[(size_t)n * 128 + t] = v > 0.f ? v : (__expf(v) - 1.f);
}

// ---------------- layer-2 features + attention logits ----------------------
__global__ __launch_bounds__(128) void feat2(
    const float* __restrict__ hmid, const float* __restrict__ W2,
    const float* __restrict__ att_s2, const float* __restrict__ att_d2,
    float* __restrict__ h2, float* __restrict__ as2, float* __restrict__ ad2) {
  const int n = blockIdx.x, t = threadIdx.x;
  float v = hmid[(size_t)n * 128 + t];
  float p0 = v * W2[2 * t], p1 = v * W2[2 * t + 1];
#pragma unroll
  for (int off = 32; off; off >>= 1) {
    p0 += __shfl_xor(p0, off);
    p1 += __shfl_xor(p1, off);
  }
  __shared__ float sred[4];
  if ((t & 63) == 0) {
    sred[(t >> 6) * 2] = p0;
    sred[(t >> 6) * 2 + 1] = p1;
  }
  __syncthreads();
  if (t == 0) {
    float h20 = sred[0] + sred[2], h21 = sred[1] + sred[3];
    h2[2 * n] = h20;
    h2[2 * n + 1] = h21;
    as2[n] = h20 * att_s2[0] + h21 * att_s2[1];
    ad2[n] = h20 * att_d2[0] + h21 * att_d2[1];
  }
}

// ---------------- layer-2 aggregation (wave per node) ----------------------
__global__ __launch_bounds__(256) void agg2(
    const float* __restrict__ h2, const float* __restrict__ as2,
    const float* __restrict__ ad2, const int* __restrict__ offsets,
    const int* __restrict__ sortedsrc, const float* __restrict__ b2,
    float* __restrict__ out, int N) {
  const int node = blockIdx.x * 4 + (threadIdx.x >> 6);
  const int lane = threadIdx.x & 63;
  if (node >= N) return;
  const int begin = offsets[node], end = offsets[node + 1];
  const float ad = ad2[node];
  float acc0 = 0.f, acc1 = 0.f, aw = 0.f;
  for (int j = begin + lane; j < end; j += 64) {
    int s = sortedsrc[j];
    float e = as2[s] + ad;
    float lr = e > 0.f ? e : NEG_SLOPE * e;
    float w = __expf(lr);
    acc0 += w * h2[2 * s];
    acc1 += w * h2[2 * s + 1];
    aw += w;
  }
#pragma unroll
  for (int off = 32; off; off >>= 1) {
    acc0 += __shfl_xor(acc0, off);
    acc1 += __shfl_xor(acc1, off);
    aw += __shfl_xor(aw, off);
  }
  if (lane == 0) {
    float inv = 1.f / (aw + 1e-16f);
    out[2 * node] = acc0 * inv + b2[0];
    out[2 * node + 1] = acc1 * inv + b2[1];
  }
}

extern "C" void kernel_launch(void* const* d_in, const int* in_sizes, int n_in,
                              void* d_out, int out_size, void* d_ws,
                              size_t ws_size, hipStream_t stream) {
  const float* x = (const float*)d_in[0];
  const int* edge_index = (const int*)d_in[1];
  const float* W1 = (const float*)d_in[2];
  const float* att_src1 = (const float*)d_in[3];
  const float* att_dst1 = (const float*)d_in[4];
  const float* b1 = (const float*)d_in[5];
  const float* Wp = (const float*)d_in[6];
  const float* bp = (const float*)d_in[7];
  const float* W2 = (const float*)d_in[8];
  const float* att_src2 = (const float*)d_in[9];
  const float* att_dst2 = (const float*)d_in[10];
  const float* b2 = (const float*)d_in[11];
  float* out = (float*)d_out;

  const int N = in_sizes[0] / 768;
  const int E = in_sizes[1] / 2;
  const int Etot = E + N;
  const int* src = edge_index;
  const int* dst = edge_index + E;

  char* ws = (char*)d_ws;
  size_t off = 0;
  auto alloc = [&](size_t bytes) {
    size_t cur = off;
    off += (bytes + 255) & ~(size_t)255;
    return (void*)(ws + cur);
  };
  float* h1lin = (float*)alloc((size_t)N * 128 * 4);
  float* proj = (float*)alloc((size_t)N * 128 * 4);
  float* hmid = (float*)alloc((size_t)N * 128 * 4);
  float* a_s1 = (float*)alloc((size_t)N * 8 * 4);
  float* a_d1 = (float*)alloc((size_t)N * 8 * 4);
  float* h2 = (float*)alloc((size_t)N * 2 * 4);
  float* as2 = (float*)alloc((size_t)N * 4);
  float* ad2 = (float*)alloc((size_t)N * 4);
  int* counts = (int*)alloc((size_t)N * 4);
  int* offsets = (int*)alloc(((size_t)N + 1) * 4);
  int* cursor = (int*)alloc((size_t)N * 4);
  int* bsum = (int*)alloc(256 * 4);
  int* sortedsrc = (int*)alloc((size_t)Etot * 4);
  short* Wt = (short*)alloc((size_t)256 * 768 * 2);

  // 0. weights -> bf16 B^T
  convert_w<<<768, 256, 0, stream>>>(W1, Wp, Wt);
  // 1. fused MFMA GEMM: h1lin = x@W1, proj = x@Wp
  gemm_mfma<<<N / 128, 256, 0, stream>>>(x, Wt, h1lin, proj);
  // 2. layer-1 attention logits
  attn1<<<N, 128, 0, stream>>>(h1lin, att_src1, att_dst1, a_s1, a_d1);
  // 3. counting sort by dst (self loops included)
  init_counts<<<(N + 255) / 256, 256, 0, stream>>>(counts, N);
  hist_kernel<<<5120, 256, 0, stream>>>(dst, counts, E);
  scan_a<<<N / 256, 256, 0, stream>>>(counts, offsets, bsum);
  scan_b<<<1, 256, 0, stream>>>(bsum);
  scan_c<<<N / 256, 256, 0, stream>>>(offsets, bsum, cursor, N, Etot);
  scatter_edges<<<5120, 256, 0, stream>>>(src, dst, cursor, sortedsrc, E);
  scatter_self<<<(N + 255) / 256, 256, 0, stream>>>(cursor, sortedsrc, N);
  // 4. layer-1 aggregation + residual + ELU
  agg1<<<N, 128, 0, stream>>>(h1lin, proj, a_s1, a_d1, offsets, sortedsrc, b1,
                              bp, hmid);
  // 5. layer-2 features + logits
  feat2<<<N, 128, 0, stream>>>(hmid, W2, att_src2, att_dst2, h2, as2, ad2);
  // 6. layer-2 aggregation -> output
  agg2<<<(N + 3) / 4, 256, 0, stream>>>(h2, as2, ad2, offsets, sortedsrc, b2,
                                        out, N);
}

// Round 3
// 584.757 us; speedup vs baseline: 1.6282x; 1.1166x over previous
//
#include <hip/hip_runtime.h>
#include <hip/hip_bf16.h>
#include <math.h>

#define NEG_SLOPE 0.2f

typedef __attribute__((ext_vector_type(8))) short short8;
typedef __attribute__((ext_vector_type(4))) float float4v;

__device__ __forceinline__ unsigned f2bf(float f) {
  unsigned u = __builtin_bit_cast(unsigned, f);
  return (u + 0x7fffu + ((u >> 16) & 1u)) >> 16;  // RNE
}
__device__ __forceinline__ float bflo(unsigned u) {
  return __builtin_bit_cast(float, u << 16);
}
__device__ __forceinline__ float bfhi(unsigned u) {
  return __builtin_bit_cast(float, u & 0xffff0000u);
}

// ---------------- weight pre-transpose: Wt[c][k] bf16, c in [0,256) --------
__global__ __launch_bounds__(256) void convert_w(const float* __restrict__ W1,
                                                 const float* __restrict__ Wp,
                                                 short* __restrict__ Wt) {
  int k = blockIdx.x;   // 0..767
  int c = threadIdx.x;  // 0..255
  float v = (c < 128) ? W1[k * 128 + c] : Wp[k * 128 + (c - 128)];
  Wt[(size_t)c * 768 + k] = (short)f2bf(v);
}

// ---------------- bf16 MFMA GEMM: [h1lin|proj] = x @ [W1|Wp] ---------------
__global__ __launch_bounds__(256) void gemm_mfma(const float* __restrict__ x,
                                                 const short* __restrict__ Wt,
                                                 float* __restrict__ h1lin,
                                                 float* __restrict__ proj) {
  __shared__ short As[128][40];
  __shared__ short Bs[256][40];
  const int tid = threadIdx.x;
  const int wave = tid >> 6, lane = tid & 63;
  const int l15 = lane & 15, l4 = lane >> 4;
  const int row0 = blockIdx.x * 128;

  const int ar = tid >> 3;
  const int ak = (tid & 7) * 4;
  const int bc = tid >> 2;
  const int bk = (tid & 3) * 8;

  float4v acc[8][4] = {};

  for (int k0 = 0; k0 < 768; k0 += 32) {
#pragma unroll
    for (int i = 0; i < 4; i++) {
      int r = i * 32 + ar;
      float4 f = *(const float4*)&x[(size_t)(row0 + r) * 768 + k0 + ak];
      uint2 p;
      p.x = f2bf(f.x) | (f2bf(f.y) << 16);
      p.y = f2bf(f.z) | (f2bf(f.w) << 16);
      *(uint2*)&As[r][ak] = p;
    }
#pragma unroll
    for (int i = 0; i < 4; i++) {
      int c = i * 64 + bc;
      uint4 v = *(const uint4*)&Wt[(size_t)c * 768 + k0 + bk];
      *(uint4*)&Bs[c][bk] = v;
    }
    __syncthreads();

    short8 afr[8];
#pragma unroll
    for (int rt = 0; rt < 8; rt++)
      afr[rt] = *(const short8*)&As[rt * 16 + l15][l4 * 8];
#pragma unroll
    for (int ct = 0; ct < 4; ct++) {
      short8 bfr = *(const short8*)&Bs[wave * 64 + ct * 16 + l15][l4 * 8];
#pragma unroll
      for (int rt = 0; rt < 8; rt++)
        acc[rt][ct] =
            __builtin_amdgcn_mfma_f32_16x16x32_bf16(afr[rt], bfr, acc[rt][ct], 0, 0, 0);
    }
    __syncthreads();
  }

  const int colbase = wave * 64;
#pragma unroll
  for (int ct = 0; ct < 4; ct++) {
    int c = colbase + ct * 16 + l15;
    float* Cout = (c < 128) ? h1lin : proj;
    int cc = c & 127;
#pragma unroll
    for (int rt = 0; rt < 8; rt++) {
#pragma unroll
      for (int r = 0; r < 4; r++) {
        int R = row0 + rt * 16 + l4 * 4 + r;
        Cout[(size_t)R * 128 + cc] = acc[rt][ct][r];
      }
    }
  }
}

// ---------------- layer-1 logits + bf16 repack of h1 -----------------------
__global__ __launch_bounds__(128) void attn1(
    const float* __restrict__ h1lin, const float* __restrict__ att_src1,
    const float* __restrict__ att_dst1, float* __restrict__ a_s1,
    float* __restrict__ a_d1, unsigned* __restrict__ h1bf) {
  const int n = blockIdx.x, t = threadIdx.x;
  float v = h1lin[(size_t)n * 128 + t];
  unsigned u = f2bf(v);
  unsigned up = __shfl_xor(u, 1);
  if ((t & 1) == 0) h1bf[n * 64 + (t >> 1)] = u | (up << 16);
  float as = v * att_src1[t];
  float ad = v * att_dst1[t];
#pragma unroll
  for (int off = 8; off; off >>= 1) {
    as += __shfl_xor(as, off);
    ad += __shfl_xor(ad, off);
  }
  if ((t & 15) == 0) {
    a_s1[n * 8 + (t >> 4)] = as;
    a_d1[n * 8 + (t >> 4)] = ad;
  }
}

// ---------------- counting sort of edges by dst ----------------------------
__global__ void init_counts(int* counts, int N) {
  int i = blockIdx.x * blockDim.x + threadIdx.x;
  if (i < N) counts[i] = 1;  // self loop
}

__global__ void hist_kernel(const int* __restrict__ dst, int* counts, int E) {
  int i = blockIdx.x * blockDim.x + threadIdx.x;
  int base = i * 4;
  if (base + 3 < E) {
    int4 d = *(const int4*)&dst[base];
    atomicAdd(&counts[d.x], 1);
    atomicAdd(&counts[d.y], 1);
    atomicAdd(&counts[d.z], 1);
    atomicAdd(&counts[d.w], 1);
  } else {
    for (int j = base; j < E; j++) atomicAdd(&counts[dst[j]], 1);
  }
}

__global__ __launch_bounds__(256) void scan_a(const int* __restrict__ counts,
                                              int* offsets, int* bsum) {
  __shared__ int s[256];
  int t = threadIdx.x, idx = blockIdx.x * 256 + t;
  int v = counts[idx];
  s[t] = v;
  __syncthreads();
  for (int d = 1; d < 256; d <<= 1) {
    int x = (t >= d) ? s[t - d] : 0;
    __syncthreads();
    s[t] += x;
    __syncthreads();
  }
  offsets[idx] = s[t] - v;
  if (t == 255) bsum[blockIdx.x] = s[t];
}

__global__ __launch_bounds__(256) void scan_b(int* bsum) {
  __shared__ int s[256];
  int t = threadIdx.x;
  int v = bsum[t];
  s[t] = v;
  __syncthreads();
  for (int d = 1; d < 256; d <<= 1) {
    int x = (t >= d) ? s[t - d] : 0;
    __syncthreads();
    s[t] += x;
    __syncthreads();
  }
  bsum[t] = s[t] - v;
}

__global__ __launch_bounds__(256) void scan_c(int* offsets, const int* bsum,
                                              int* cursor, int N, int Etot) {
  int t = threadIdx.x, idx = blockIdx.x * 256 + t;
  int off = offsets[idx] + bsum[blockIdx.x];
  offsets[idx] = off;
  cursor[idx] = off;
  if (idx == 0) offsets[N] = Etot;
}

__global__ void scatter_edges(const int* __restrict__ src,
                              const int* __restrict__ dst, int* cursor,
                              int* sortedsrc, int E) {
  int i = blockIdx.x * blockDim.x + threadIdx.x;
  int base = i * 4;
  if (base + 3 < E) {
    int4 s = *(const int4*)&src[base];
    int4 d = *(const int4*)&dst[base];
    sortedsrc[atomicAdd(&cursor[d.x], 1)] = s.x;
    sortedsrc[atomicAdd(&cursor[d.y], 1)] = s.y;
    sortedsrc[atomicAdd(&cursor[d.z], 1)] = s.z;
    sortedsrc[atomicAdd(&cursor[d.w], 1)] = s.w;
  } else {
    for (int j = base; j < E; j++)
      sortedsrc[atomicAdd(&cursor[dst[j]], 1)] = src[j];
  }
}

__global__ void scatter_self(int* cursor, int* sortedsrc, int N) {
  int i = blockIdx.x * blockDim.x + threadIdx.x;
  if (i < N) {
    int pos = atomicAdd(&cursor[i], 1);
    sortedsrc[pos] = i;
  }
}

// ---------------- layer-1 aggregation + residual + ELU + layer-2 feat ------
// 4 nodes/block, 32 threads/node, 4 channels/thread (uint2 bf16 gathers).
// Fused feat2: h2/as2/ad2 produced here; hmid never materialized.
__global__ __launch_bounds__(128) void agg1_fused(
    const unsigned* __restrict__ h1bf, const float* __restrict__ proj,
    const float* __restrict__ a_s1, const float* __restrict__ a_d1,
    const int* __restrict__ offsets, const int* __restrict__ sortedsrc,
    const float* __restrict__ b1, const float* __restrict__ bp,
    const float* __restrict__ W2, const float* __restrict__ att_s2,
    const float* __restrict__ att_d2, float* __restrict__ h2,
    float* __restrict__ as2, float* __restrict__ ad2) {
  const int t = threadIdx.x;
  const int n = blockIdx.x * 4 + (t >> 5);
  const int k = t & 31;  // channel group: channels 4k..4k+3
  const int h = k >> 2;  // head
  const float ad = a_d1[n * 8 + h];
  const int begin = offsets[n], end = offsets[n + 1];
  float acc0 = 0.f, acc1 = 0.f, acc2 = 0.f, acc3 = 0.f, aw = 0.f;
  int j = begin;
  for (; j + 2 <= end; j += 2) {
    int s0 = sortedsrc[j], s1 = sortedsrc[j + 1];
    float e0 = a_s1[s0 * 8 + h], e1 = a_s1[s1 * 8 + h];
    uint2 q0 = *(const uint2*)&h1bf[(size_t)s0 * 64 + k * 2];
    uint2 q1 = *(const uint2*)&h1bf[(size_t)s1 * 64 + k * 2];
    e0 += ad;
    e1 += ad;
    float w0 = __expf(e0 > 0.f ? e0 : NEG_SLOPE * e0);
    float w1 = __expf(e1 > 0.f ? e1 : NEG_SLOPE * e1);
    acc0 += w0 * bflo(q0.x) + w1 * bflo(q1.x);
    acc1 += w0 * bfhi(q0.x) + w1 * bfhi(q1.x);
    acc2 += w0 * bflo(q0.y) + w1 * bflo(q1.y);
    acc3 += w0 * bfhi(q0.y) + w1 * bfhi(q1.y);
    aw += w0 + w1;
  }
  if (j < end) {
    int s0 = sortedsrc[j];
    float e0 = a_s1[s0 * 8 + h] + ad;
    uint2 q0 = *(const uint2*)&h1bf[(size_t)s0 * 64 + k * 2];
    float w0 = __expf(e0 > 0.f ? e0 : NEG_SLOPE * e0);
    acc0 += w0 * bflo(q0.x);
    acc1 += w0 * bfhi(q0.x);
    acc2 += w0 * bflo(q0.y);
    acc3 += w0 * bfhi(q0.y);
    aw += w0;
  }
  const float inv = 1.f / (aw + 1e-16f);
  const float4 pj = *(const float4*)&proj[(size_t)n * 128 + k * 4];
  const float4 B1 = *(const float4*)&b1[k * 4];
  const float4 BP = *(const float4*)&bp[k * 4];
  float v0 = acc0 * inv + pj.x + B1.x + BP.x;
  float v1 = acc1 * inv + pj.y + B1.y + BP.y;
  float v2 = acc2 * inv + pj.z + B1.z + BP.z;
  float v3 = acc3 * inv + pj.w + B1.w + BP.w;
  v0 = v0 > 0.f ? v0 : (__expf(v0) - 1.f);
  v1 = v1 > 0.f ? v1 : (__expf(v1) - 1.f);
  v2 = v2 > 0.f ? v2 : (__expf(v2) - 1.f);
  v3 = v3 > 0.f ? v3 : (__expf(v3) - 1.f);
  // layer-2 features: p = sum_c v[c] * W2[c][:]
  float2 w20 = *(const float2*)&W2[(k * 4 + 0) * 2];
  float2 w21 = *(const float2*)&W2[(k * 4 + 1) * 2];
  float2 w22 = *(const float2*)&W2[(k * 4 + 2) * 2];
  float2 w23 = *(const float2*)&W2[(k * 4 + 3) * 2];
  float p0 = v0 * w20.x + v1 * w21.x + v2 * w22.x + v3 * w23.x;
  float p1 = v0 * w20.y + v1 * w21.y + v2 * w22.y + v3 * w23.y;
#pragma unroll
  for (int off = 16; off; off >>= 1) {
    p0 += __shfl_xor(p0, off);
    p1 += __shfl_xor(p1, off);
  }
  if (k == 0) {
    h2[2 * n] = p0;
    h2[2 * n + 1] = p1;
    as2[n] = p0 * att_s2[0] + p1 * att_s2[1];
    ad2[n] = p0 * att_d2[0] + p1 * att_d2[1];
  }
}

// ---------------- layer-2 aggregation (16 lanes per node) ------------------
__global__ __launch_bounds__(256) void agg2(
    const float* __restrict__ h2, const float* __restrict__ as2,
    const float* __restrict__ ad2, const int* __restrict__ offsets,
    const int* __restrict__ sortedsrc, const float* __restrict__ b2,
    float* __restrict__ out, int N) {
  const int node = blockIdx.x * 16 + (threadIdx.x >> 4);
  const int lane = threadIdx.x & 15;
  const int begin = offsets[node], end = offsets[node + 1];
  const float ad = ad2[node];
  float acc0 = 0.f, acc1 = 0.f, aw = 0.f;
  for (int j = begin + lane; j < end; j += 16) {
    int s = sortedsrc[j];
    float e = as2[s] + ad;
    float w = __expf(e > 0.f ? e : NEG_SLOPE * e);
    float2 hh = *(const float2*)&h2[2 * s];
    acc0 += w * hh.x;
    acc1 += w * hh.y;
    aw += w;
  }
#pragma unroll
  for (int off = 8; off; off >>= 1) {
    acc0 += __shfl_xor(acc0, off);
    acc1 += __shfl_xor(acc1, off);
    aw += __shfl_xor(aw, off);
  }
  if (lane == 0) {
    float inv = 1.f / (aw + 1e-16f);
    out[2 * node] = acc0 * inv + b2[0];
    out[2 * node + 1] = acc1 * inv + b2[1];
  }
}

extern "C" void kernel_launch(void* const* d_in, const int* in_sizes, int n_in,
                              void* d_out, int out_size, void* d_ws,
                              size_t ws_size, hipStream_t stream) {
  const float* x = (const float*)d_in[0];
  const int* edge_index = (const int*)d_in[1];
  const float* W1 = (const float*)d_in[2];
  const float* att_src1 = (const float*)d_in[3];
  const float* att_dst1 = (const float*)d_in[4];
  const float* b1 = (const float*)d_in[5];
  const float* Wp = (const float*)d_in[6];
  const float* bp = (const float*)d_in[7];
  const float* W2 = (const float*)d_in[8];
  const float* att_src2 = (const float*)d_in[9];
  const float* att_dst2 = (const float*)d_in[10];
  const float* b2 = (const float*)d_in[11];
  float* out = (float*)d_out;

  const int N = in_sizes[0] / 768;
  const int E = in_sizes[1] / 2;
  const int Etot = E + N;
  const int* src = edge_index;
  const int* dst = edge_index + E;

  char* ws = (char*)d_ws;
  size_t off = 0;
  auto alloc = [&](size_t bytes) {
    size_t cur = off;
    off += (bytes + 255) & ~(size_t)255;
    return (void*)(ws + cur);
  };
  float* h1lin = (float*)alloc((size_t)N * 128 * 4);
  float* proj = (float*)alloc((size_t)N * 128 * 4);
  unsigned* h1bf = (unsigned*)alloc((size_t)N * 64 * 4);
  float* a_s1 = (float*)alloc((size_t)N * 8 * 4);
  float* a_d1 = (float*)alloc((size_t)N * 8 * 4);
  float* h2 = (float*)alloc((size_t)N * 2 * 4);
  float* as2 = (float*)alloc((size_t)N * 4);
  float* ad2 = (float*)alloc((size_t)N * 4);
  int* counts = (int*)alloc((size_t)N * 4);
  int* offsets = (int*)alloc(((size_t)N + 1) * 4);
  int* cursor = (int*)alloc((size_t)N * 4);
  int* bsum = (int*)alloc(256 * 4);
  int* sortedsrc = (int*)alloc((size_t)Etot * 4);
  short* Wt = (short*)alloc((size_t)256 * 768 * 2);

  // 0. weights -> bf16 B^T
  convert_w<<<768, 256, 0, stream>>>(W1, Wp, Wt);
  // 1. fused MFMA GEMM
  gemm_mfma<<<N / 128, 256, 0, stream>>>(x, Wt, h1lin, proj);
  // 2. layer-1 logits + bf16 repack
  attn1<<<N, 128, 0, stream>>>(h1lin, att_src1, att_dst1, a_s1, a_d1, h1bf);
  // 3. counting sort by dst
  init_counts<<<(N + 255) / 256, 256, 0, stream>>>(counts, N);
  hist_kernel<<<(E / 4 + 255) / 256, 256, 0, stream>>>(dst, counts, E);
  scan_a<<<N / 256, 256, 0, stream>>>(counts, offsets, bsum);
  scan_b<<<1, 256, 0, stream>>>(bsum);
  scan_c<<<N / 256, 256, 0, stream>>>(offsets, bsum, cursor, N, Etot);
  scatter_edges<<<(E / 4 + 255) / 256, 256, 0, stream>>>(src, dst, cursor,
                                                         sortedsrc, E);
  scatter_self<<<(N + 255) / 256, 256, 0, stream>>>(cursor, sortedsrc, N);
  // 4. layer-1 aggregation + residual + ELU + layer-2 features (fused)
  agg1_fused<<<N / 4, 128, 0, stream>>>(h1bf, proj, a_s1, a_d1, offsets,
                                        sortedsrc, b1, bp, W2, att_src2,
                                        att_dst2, h2, as2, ad2);
  // 5. layer-2 aggregation -> output
  agg2<<<N / 16, 256, 0, stream>>>(h2, as2, ad2, offsets, sortedsrc, b2, out,
                                   N);
}